// Round 1
// baseline (887.680 us; speedup 1.0000x reference)
//
#include <hip/hip_runtime.h>
#include <hip/hip_bf16.h>
#include <math.h>

typedef unsigned short u16;
typedef __attribute__((ext_vector_type(4))) float f32x4;
typedef __attribute__((ext_vector_type(8))) short bf16x8;

#define GLD16(gptr, lptr) __builtin_amdgcn_global_load_lds( \
    (const __attribute__((address_space(1))) void*)(gptr),  \
    (__attribute__((address_space(3))) void*)(lptr), 16, 0, 0)

__device__ __forceinline__ float bf2f(u16 u) {
  union { unsigned int i; float f; } c; c.i = ((unsigned int)u) << 16; return c.f;
}
__device__ __forceinline__ u16 f2bf(float f) {
  union { float f; unsigned int i; } c; c.f = f;
  unsigned int r = c.i + 0x7fffu + ((c.i >> 16) & 1u);
  return (u16)(r >> 16);
}

// ---------------- fp32 -> bf16 elementwise (float4 vectorized) ----------------
__global__ __launch_bounds__(256) void f32_to_bf16(const float* __restrict__ in,
                                                   u16* __restrict__ out, int n4) {
  int i = blockIdx.x * 256 + threadIdx.x;
  if (i >= n4) return;
  float4 v = reinterpret_cast<const float4*>(in)[i];
  ushort4 o;
  o.x = f2bf(v.x); o.y = f2bf(v.y); o.z = f2bf(v.z); o.w = f2bf(v.w);
  reinterpret_cast<ushort4*>(out)[i] = o;
}

// ---------------- W[K][N] fp32 -> Wt[N][K] bf16 (tiled transpose) ----------------
__global__ __launch_bounds__(256) void transpose_convert(const float* __restrict__ W,
                                                         u16* __restrict__ Wt,
                                                         int K, int N) {
  __shared__ float tile[32][33];
  const int n0 = blockIdx.x * 32, k0 = blockIdx.y * 32;
  const int tx = threadIdx.x & 31, ty = threadIdx.x >> 5;
#pragma unroll
  for (int r = 0; r < 32; r += 8)
    tile[ty + r][tx] = W[(size_t)(k0 + ty + r) * N + (n0 + tx)];
  __syncthreads();
#pragma unroll
  for (int r = 0; r < 32; r += 8)
    Wt[(size_t)(n0 + ty + r) * K + (k0 + tx)] = f2bf(tile[tx][ty + r]);
}

// ---------------- RoPE in-place on bf16 [T][nheads*128] ----------------
__global__ __launch_bounds__(256) void rope_kernel(u16* __restrict__ X, int nheads,
                                                   const int* __restrict__ pos_ptr) {
  int idx = blockIdx.x * 256 + threadIdx.x;
  int total = 2048 * nheads * 64;
  if (idx >= total) return;
  int d = idx & 63;
  int h = (idx >> 6) % nheads;
  int t = idx / (64 * nheads);
  int pos = *pos_ptr;
  float inv = powf(500000.0f, -(float)d * (1.0f / 64.0f));
  float ang = (float)(pos + t) * inv;
  float c = cosf(ang), s = sinf(ang);
  size_t base = (size_t)t * nheads * 128 + h * 128 + d;
  float x1 = bf2f(X[base]);
  float x2 = bf2f(X[base + 64]);
  X[base]      = f2bf(x1 * c - x2 * s);
  X[base + 64] = f2bf(x2 * c + x1 * s);
}

// ---------------- bf16 GEMM: C[M][N] = A[M][K] @ Bt[N][K]^T ----------------
// 128x128 tile, BK=32, 4 waves (each 64x64 of 16x16 frags), global_load_lds staging.
template <int OUT_BF16>
__global__ __launch_bounds__(256) void gemm_bt(const u16* __restrict__ A,
                                               const u16* __restrict__ Bt,
                                               void* __restrict__ C,
                                               int M, int N, int K) {
  __shared__ alignas(16) u16 As[128 * 32];
  __shared__ alignas(16) u16 Bs[128 * 32];
  const int tid = threadIdx.x;
  const int w = tid >> 6, lane = tid & 63;
  const int l15 = lane & 15, lg = lane >> 4;
  const int wr = w >> 1, wc = w & 1;
  const int m0 = blockIdx.y * 128, n0 = blockIdx.x * 128;
  const int srow = lane >> 2;          // 0..15
  const int scol = (lane & 3) * 8;     // 0,8,16,24

  f32x4 acc[4][4];
#pragma unroll
  for (int i = 0; i < 4; ++i)
#pragma unroll
    for (int j = 0; j < 4; ++j) {
      f32x4 z = {0.f, 0.f, 0.f, 0.f};
      acc[i][j] = z;
    }

  for (int k0 = 0; k0 < K; k0 += 32) {
#pragma unroll
    for (int p = 0; p < 2; ++p) {
      const int rbase = w * 32 + p * 16;
      GLD16(A  + (size_t)(m0 + rbase + srow) * K + k0 + scol, &As[rbase * 32]);
      GLD16(Bt + (size_t)(n0 + rbase + srow) * K + k0 + scol, &Bs[rbase * 32]);
    }
    __syncthreads();
    bf16x8 af[4], bfr[4];
#pragma unroll
    for (int i = 0; i < 4; ++i)
      af[i] = *reinterpret_cast<const bf16x8*>(&As[(wr * 64 + i * 16 + l15) * 32 + lg * 8]);
#pragma unroll
    for (int j = 0; j < 4; ++j)
      bfr[j] = *reinterpret_cast<const bf16x8*>(&Bs[(wc * 64 + j * 16 + l15) * 32 + lg * 8]);
#pragma unroll
    for (int i = 0; i < 4; ++i)
#pragma unroll
      for (int j = 0; j < 4; ++j)
        acc[i][j] = __builtin_amdgcn_mfma_f32_16x16x32_bf16(af[i], bfr[j], acc[i][j], 0, 0, 0);
    __syncthreads();
  }

#pragma unroll
  for (int i = 0; i < 4; ++i)
#pragma unroll
    for (int j = 0; j < 4; ++j)
#pragma unroll
      for (int r = 0; r < 4; ++r) {
        const int row = m0 + wr * 64 + i * 16 + lg * 4 + r;
        const int col = n0 + wc * 64 + j * 16 + l15;
        const float v = acc[i][j][r];
        if (OUT_BF16) ((u16*)C)[(size_t)row * N + col] = f2bf(v);
        else          ((float*)C)[(size_t)row * N + col] = v;
      }
}

// ---------------- GQA causal flash attention ----------------
// grid (T/64, H). 4 waves, each owns 16 q-rows. KV tiles of 32, online softmax.
__global__ __launch_bounds__(256) void attn_kernel(const u16* __restrict__ Q,
                                                   const u16* __restrict__ K,
                                                   const u16* __restrict__ V,
                                                   u16* __restrict__ O,
                                                   const int* __restrict__ pos_ptr) {
  const int pos = *pos_ptr;
  const int h = blockIdx.y;
  const int hkv = h >> 2;           // H/HKV = 4
  const int tid = threadIdx.x;
  const int w = tid >> 6;
  const int lane = tid & 63;
  const int l15 = lane & 15;
  const int lg = lane >> 4;

  __shared__ alignas(16) u16 Ks[32][136];   // K tile, +8 pad
  __shared__ alignas(16) u16 Vt[128][40];   // V^T tile, +8 pad
  __shared__ alignas(16) u16 Pl[4][16][40]; // per-wave P staging

  const int qt0 = blockIdx.x * 64;
  const int qrow_frag = qt0 + w * 16 + l15;
  bf16x8 qa[4];
#pragma unroll
  for (int kk = 0; kk < 4; ++kk)
    qa[kk] = *reinterpret_cast<const bf16x8*>(Q + (size_t)qrow_frag * 4096 + h * 128 + kk * 32 + lg * 8);

  f32x4 acc[8];
#pragma unroll
  for (int i = 0; i < 8; ++i) { f32x4 z = {0.f, 0.f, 0.f, 0.f}; acc[i] = z; }
  float mrun[4], lrun[4];
#pragma unroll
  for (int r = 0; r < 4; ++r) {
    mrun[r] = (pos > 0) ? 0.0f : -INFINITY;  // zero-key prefix contributes logit 0
    lrun[r] = (float)pos;                    // ... pos times, value 0
  }

  const int qrow_c = qt0 + w * 16 + lg * 4;
  const int nst = 2 * blockIdx.x + 2;
  const float scale = 0.08838834764831845f;  // 1/sqrt(128)

  for (int st = 0; st < nst; ++st) {
    const int s0 = st * 32;
    // ---- stage K[32][128] and V^T[128][32] ----
#pragma unroll
    for (int p = 0; p < 2; ++p) {
      const int q8 = tid + p * 256;
      const int sr = q8 >> 4;
      const int c8 = (q8 & 15) * 8;
      const size_t gsrc = (size_t)(s0 + sr) * 1024 + hkv * 128 + c8;
      bf16x8 kv = *reinterpret_cast<const bf16x8*>(K + gsrc);
      *reinterpret_cast<bf16x8*>(&Ks[sr][c8]) = kv;
      bf16x8 vv = *reinterpret_cast<const bf16x8*>(V + gsrc);
#pragma unroll
      for (int e = 0; e < 8; ++e) Vt[c8 + e][sr] = (u16)vv[e];
    }
    __syncthreads();

    // ---- QK^T: two 16x16 s-subtiles, K-chained over D=128 ----
    float pv[2][4];
#pragma unroll
    for (int sub = 0; sub < 2; ++sub) {
      f32x4 s4 = {0.f, 0.f, 0.f, 0.f};
#pragma unroll
      for (int kk = 0; kk < 4; ++kk) {
        bf16x8 kf = *reinterpret_cast<const bf16x8*>(&Ks[sub * 16 + l15][kk * 32 + lg * 8]);
        s4 = __builtin_amdgcn_mfma_f32_16x16x32_bf16(qa[kk], kf, s4, 0, 0, 0);
      }
#pragma unroll
      for (int r = 0; r < 4; ++r) pv[sub][r] = s4[r];
    }

    // ---- online softmax (per q-row, 16-lane reductions) ----
    float sf[4];
#pragma unroll
    for (int r = 0; r < 4; ++r) {
      const int qrow = qrow_c + r;
      float mx = -INFINITY;
#pragma unroll
      for (int sub = 0; sub < 2; ++sub) {
        const int scol = s0 + sub * 16 + l15;
        float v = pv[sub][r] * scale;
        v = (scol <= qrow) ? v : -INFINITY;
        pv[sub][r] = v;
        mx = fmaxf(mx, v);
      }
#pragma unroll
      for (int off = 1; off < 16; off <<= 1) mx = fmaxf(mx, __shfl_xor(mx, off));
      const float mnew = fmaxf(mrun[r], mx);
      const float scf = __expf(mrun[r] - mnew);
      sf[r] = scf;
      float psum = 0.0f;
#pragma unroll
      for (int sub = 0; sub < 2; ++sub) {
        const float p = __expf(pv[sub][r] - mnew);
        pv[sub][r] = p;
        psum += p;
      }
#pragma unroll
      for (int off = 1; off < 16; off <<= 1) psum += __shfl_xor(psum, off);
      lrun[r] = lrun[r] * scf + psum;
      mrun[r] = mnew;
    }
#pragma unroll
    for (int dc = 0; dc < 8; ++dc)
#pragma unroll
      for (int r = 0; r < 4; ++r) acc[dc][r] *= sf[r];

    // ---- P -> LDS (D-layout write, A-layout read) ----
#pragma unroll
    for (int sub = 0; sub < 2; ++sub)
#pragma unroll
      for (int r = 0; r < 4; ++r)
        Pl[w][lg * 4 + r][sub * 16 + l15] = f2bf(pv[sub][r]);
    __syncthreads();

    // ---- PV: acc[16q][128d] += P[16][32] @ V[32][128] ----
    bf16x8 pf = *reinterpret_cast<const bf16x8*>(&Pl[w][l15][lg * 8]);
#pragma unroll
    for (int dc = 0; dc < 8; ++dc) {
      bf16x8 vf = *reinterpret_cast<const bf16x8*>(&Vt[dc * 16 + l15][lg * 8]);
      acc[dc] = __builtin_amdgcn_mfma_f32_16x16x32_bf16(pf, vf, acc[dc], 0, 0, 0);
    }
    __syncthreads();
  }

#pragma unroll
  for (int dc = 0; dc < 8; ++dc)
#pragma unroll
    for (int r = 0; r < 4; ++r) {
      const int qrow = qrow_c + r;
      O[(size_t)qrow * 4096 + h * 128 + dc * 16 + l15] = f2bf(acc[dc][r] / lrun[r]);
    }
}

extern "C" void kernel_launch(void* const* d_in, const int* in_sizes, int n_in,
                              void* d_out, int out_size, void* d_ws, size_t ws_size,
                              hipStream_t stream) {
  const float* hs = (const float*)d_in[0];
  const float* Wq = (const float*)d_in[1];
  const float* Wk = (const float*)d_in[2];
  const float* Wv = (const float*)d_in[3];
  const float* Wo = (const float*)d_in[4];
  const int* pos  = (const int*)d_in[5];

  char* ws = (char*)d_ws;
  // layout (bytes), peak 92,274,688:
  u16* Qb    = (u16*)(ws + 0);           // 2048*4096 bf16
  u16* Kb    = (u16*)(ws + 16777216ULL); // 2048*1024
  u16* Vb    = (u16*)(ws + 20971520ULL); // 2048*1024
  u16* WqT   = (u16*)(ws + 25165824ULL); // 4096*4096
  u16* attn  = WqT;                      // aliases WqT after QKV GEMMs done
  u16* hs_bf = (u16*)(ws + 58720256ULL); // 2048*4096
  u16* WkT   = (u16*)(ws + 75497472ULL); // 1024*4096
  u16* WvT   = (u16*)(ws + 83886080ULL); // 1024*4096
  u16* WoT   = (u16*)(ws + 58720256ULL); // aliases hs_bf+WkT+WvT after QKV GEMMs

  f32_to_bf16<<<8192, 256, 0, stream>>>(hs, hs_bf, 2097152);
  transpose_convert<<<dim3(128, 128), 256, 0, stream>>>(Wq, WqT, 4096, 4096);
  transpose_convert<<<dim3(32, 128), 256, 0, stream>>>(Wk, WkT, 4096, 1024);
  transpose_convert<<<dim3(32, 128), 256, 0, stream>>>(Wv, WvT, 4096, 1024);

  gemm_bt<1><<<dim3(32, 16), 256, 0, stream>>>(hs_bf, WqT, Qb, 2048, 4096, 4096);
  gemm_bt<1><<<dim3(8, 16), 256, 0, stream>>>(hs_bf, WkT, Kb, 2048, 1024, 4096);
  gemm_bt<1><<<dim3(8, 16), 256, 0, stream>>>(hs_bf, WvT, Vb, 2048, 1024, 4096);

  // Wo transpose AFTER QKV GEMMs: WoT overwrites hs_bf/WkT/WvT (now dead)
  transpose_convert<<<dim3(128, 128), 256, 0, stream>>>(Wo, WoT, 4096, 4096);

  rope_kernel<<<16384, 256, 0, stream>>>(Qb, 32, pos);
  rope_kernel<<<4096, 256, 0, stream>>>(Kb, 8, pos);

  attn_kernel<<<dim3(32, 32), 256, 0, stream>>>(Qb, Kb, Vb, attn, pos);

  gemm_bt<0><<<dim3(32, 16), 256, 0, stream>>>(attn, WoT, d_out, 2048, 4096, 4096);
}